// Round 1
// baseline (1617.712 us; speedup 1.0000x reference)
//
#include <hip/hip_runtime.h>
#include <math.h>

#define NC    30
#define D     300
#define WIN   100
#define TOPK  25
#define NEGV  -1e10f
#define DS    40      // d-slice per dg group (8 * 40 = 320 >= 300)

__global__ __launch_bounds__(256, 3)
void fused_mention_kernel(const float* __restrict__ E,
                          const float* __restrict__ T,
                          const void*  __restrict__ maskp,
                          const float* __restrict__ B1,
                          const float* __restrict__ B2,
                          float* __restrict__ out)
{
    const int n    = blockIdx.x;
    const int tid  = threadIdx.x;
    const int dg   = tid >> 5;        // 0..7  d-slice group
    const int cg   = tid & 31;        // 0..31 candidate (30 real + 2 pad)
    const int wv   = tid >> 6;        // wave id 0..3 (= dg>>1)
    const int lane = tid & 63;
    const int d0   = dg * DS;

    __shared__ float part[4][32][WIN];   // 51.2 KB: per-wave partial scores
    __shared__ float ts[WIN];
    __shared__ int   vld[WIN];
    __shared__ float bscore[TOPK];
    __shared__ int   bidx[TOPK];
    __shared__ float bprob[TOPK];
    __shared__ float vred[4][32];
    __shared__ int   mmode;

    // ---- mask dtype detection: int32 has zero bytes at offsets %4 != 0 ----
    if (tid == 0) mmode = 0;
    __syncthreads();
    {
        const unsigned char* mb = (const unsigned char*)maskp;
        int found = 0;
        for (int i = tid; i < 4096; i += 256)
            if ((i & 3) && mb[i]) found = 1;
        if (found) mmode = 1;
    }
    __syncthreads();
    const int bytemask = mmode;

    // ---- per-token valid flags ----
    if (tid < WIN) {
        int v;
        if (bytemask) v = ((const unsigned char*)maskp)[(size_t)n * WIN + tid] != 0;
        else          v = ((const int*)maskp)[(size_t)n * WIN + tid] != 0;
        vld[tid] = v;
    }
    __syncthreads();

    // ---- load E slice into registers, fold B_diag2 ----
    float4 e[10];
    #pragma unroll
    for (int j = 0; j < 10; ++j) e[j] = make_float4(0.f, 0.f, 0.f, 0.f);
    if (cg < NC) {
        const float* Erow = E + ((size_t)n * NC + cg) * D + d0;
        #pragma unroll
        for (int j = 0; j < 10; ++j) {
            if (j < 5 || d0 + 4 * j < D) {
                float4 ev = *reinterpret_cast<const float4*>(Erow + 4 * j);
                float4 bv = *reinterpret_cast<const float4*>(B2 + d0 + 4 * j);
                e[j].x = ev.x * bv.x; e[j].y = ev.y * bv.y;
                e[j].z = ev.z * bv.z; e[j].w = ev.w * bv.w;
            }
        }
    }

    // ---- score GEMM over valid tokens only ----
    const float* Tn = T + (size_t)n * WIN * D;
    for (int w = 0; w < WIN; ++w) {
        if (!vld[w]) continue;                 // uniform branch: skip ~50% of work
        const float* Trow = Tn + w * D + d0;
        float acc = 0.f;
        #pragma unroll
        for (int j = 0; j < 10; ++j) {
            if (j < 5 || d0 + 4 * j < D) {
                float4 t4 = *reinterpret_cast<const float4*>(Trow + 4 * j);
                acc += e[j].x * t4.x + e[j].y * t4.y + e[j].z * t4.z + e[j].w * t4.w;
            }
        }
        acc += __shfl_xor(acc, 32);
        if (lane < 32) part[wv][cg][w] = acc;
    }
    __syncthreads();

    // ---- token score = max over candidates, masked ----
    if (tid < WIN) {
        float m = NEGV;
        if (vld[tid]) {
            m = -__builtin_inff();
            for (int c = 0; c < NC; ++c) {
                float s = part[0][c][tid] + part[1][c][tid]
                        + part[2][c][tid] + part[3][c][tid];
                m = fmaxf(m, s);
            }
        }
        ts[tid] = m;
    }
    __syncthreads();

    // ---- top-25 (wave 0, register-resident, lower-index tie-break) + softmax ----
    if (tid < 64) {
        float va = ts[tid];
        float vb = (tid + 64 < WIN) ? ts[tid + 64] : -__builtin_inff();
        float mx = 0.f;
        for (int t = 0; t < TOPK; ++t) {
            float v0; int i0;
            if (vb > va) { v0 = vb; i0 = tid + 64; } else { v0 = va; i0 = tid; }
            #pragma unroll
            for (int s = 32; s >= 1; s >>= 1) {
                float ov = __shfl_xor(v0, s);
                int   oi = __shfl_xor(i0, s);
                if (ov > v0 || (ov == v0 && oi < i0)) { v0 = ov; i0 = oi; }
            }
            if (t == 0) mx = v0;
            if (tid == 0) { bscore[t] = v0; bidx[t] = i0; }
            if (i0 == tid) va = -__builtin_inff();
            else if (i0 == tid + 64) vb = -__builtin_inff();
        }
        float sc = (tid < TOPK) ? bscore[tid] : 0.f;
        float p  = (tid < TOPK) ? expf(sc - mx) : 0.f;
        float s1 = p;
        #pragma unroll
        for (int s = 32; s >= 1; s >>= 1) s1 += __shfl_xor(s1, s);
        p = p / s1;
        float s2 = p;   // reference renormalizes a second time
        #pragma unroll
        for (int s = 32; s >= 1; s >>= 1) s2 += __shfl_xor(s2, s);
        p = p / s2;
        if (tid < TOPK) bprob[tid] = p;
    }
    __syncthreads();

    // ---- fcs: probability-weighted sum of best tokens (per d-slice, in regs) ----
    float4 fc[10];
    #pragma unroll
    for (int j = 0; j < 10; ++j) fc[j] = make_float4(0.f, 0.f, 0.f, 0.f);
    for (int t = 0; t < TOPK; ++t) {
        const float p = bprob[t];
        const float* Trow = Tn + bidx[t] * D + d0;
        #pragma unroll
        for (int j = 0; j < 10; ++j) {
            if (j < 5 || d0 + 4 * j < D) {
                float4 t4 = *reinterpret_cast<const float4*>(Trow + 4 * j);
                fc[j].x += p * t4.x; fc[j].y += p * t4.y;
                fc[j].z += p * t4.z; fc[j].w += p * t4.w;
            }
        }
    }

    // ---- vals[c] = sum_d E_raw[c,d] * B1[d] * fcs[d] ----
    float acc2 = 0.f;
    if (cg < NC) {
        const float* Erow = E + ((size_t)n * NC + cg) * D + d0;
        #pragma unroll
        for (int j = 0; j < 10; ++j) {
            if (j < 5 || d0 + 4 * j < D) {
                float4 ev = *reinterpret_cast<const float4*>(Erow + 4 * j);
                float4 bv = *reinterpret_cast<const float4*>(B1 + d0 + 4 * j);
                acc2 += ev.x * bv.x * fc[j].x + ev.y * bv.y * fc[j].y
                      + ev.z * bv.z * fc[j].z + ev.w * bv.w * fc[j].w;
            }
        }
    }
    acc2 += __shfl_xor(acc2, 32);
    if (lane < 32) vred[wv][cg] = acc2;
    __syncthreads();
    if (tid < NC) {
        out[(size_t)n * NC + tid] =
            vred[0][tid] + vred[1][tid] + vred[2][tid] + vred[3][tid];
    }
}

extern "C" void kernel_launch(void* const* d_in, const int* in_sizes, int n_in,
                              void* d_out, int out_size, void* d_ws, size_t ws_size,
                              hipStream_t stream)
{
    const float* E  = (const float*)d_in[0];
    const float* T  = (const float*)d_in[1];
    const void*  M  = d_in[2];
    const float* B1 = (const float*)d_in[3];
    const float* B2 = (const float*)d_in[4];
    float* out = (float*)d_out;
    const int n = in_sizes[0] / (NC * D);   // number of mentions
    fused_mention_kernel<<<n, 256, 0, stream>>>(E, T, M, B1, B2, out);
}

// Round 2
// 1061.221 us; speedup vs baseline: 1.5244x; 1.5244x over previous
//
#include <hip/hip_runtime.h>
#include <math.h>

#define NC    30
#define D     300
#define WIN   100
#define TOPK  25
#define NEGV  -1e10f

__global__ __launch_bounds__(256, 3)
void fused_mention_kernel(const float* __restrict__ E,
                          const float* __restrict__ T,
                          const void*  __restrict__ maskp,
                          const float* __restrict__ B1,
                          const float* __restrict__ B2,
                          float* __restrict__ out)
{
    const int n    = blockIdx.x;
    const int tid  = threadIdx.x;
    const int dg   = tid >> 5;        // 0..7  d-slice group
    const int cg   = tid & 31;        // 0..31 candidate (30 real + 2 pad)
    const int wv   = tid >> 6;        // wave id 0..3
    const int lane = tid & 63;
    const int d0   = dg * 40;         // groups 0..6: 40 floats; group 7: 20 (280..300)
    const bool cok  = (cg < NC);
    const bool full = (dg < 7);
    const float cmask = cok ? 1.f : 0.f;

    __shared__ float part[4][32][101];   // 101 stride: gcd(101,32)=1 -> conflict-free
    __shared__ float ts[WIN];
    __shared__ float bscore[TOPK];
    __shared__ int   bidx[TOPK];
    __shared__ float bprob[TOPK];
    __shared__ float vred[4][32];
    __shared__ int   mmode;
    __shared__ int   lcnt[2];

    // ---- mask dtype detection: int32 has zero bytes at offsets %4 != 0 ----
    if (tid == 0) mmode = 0;
    __syncthreads();
    {
        const unsigned char* mb = (const unsigned char*)maskp;
        int found = 0;
        for (int i = tid; i < 4096; i += 256)
            if ((i & 3) && mb[i]) found = 1;
        if (found) mmode = 1;
    }
    __syncthreads();

    // ---- valid-prefix length L (mask is arange < len) via 2-wave ballot ----
    if (tid < 128) {
        int v = 0;
        if (tid < WIN) {
            if (mmode) v = ((const unsigned char*)maskp)[(size_t)n * WIN + tid] != 0;
            else       v = ((const int*)maskp)[(size_t)n * WIN + tid] != 0;
        }
        unsigned long long b = __ballot(v);
        if (lane == 0) lcnt[wv] = __popcll(b);
    }
    __syncthreads();
    const int L = lcnt[0] + lcnt[1];

    // ---- E slice -> registers, fold B_diag2 (batched, compile-time counts) ----
    float4 e[10];
    {
        const float* Erow = E + ((size_t)n * NC + (cok ? cg : 0)) * D + d0;
        float4 ev[10], bv[10];
        #pragma unroll
        for (int j = 0; j < 5; ++j) {
            ev[j] = *reinterpret_cast<const float4*>(Erow + 4 * j);
            bv[j] = *reinterpret_cast<const float4*>(B2 + d0 + 4 * j);
        }
        if (full) {
            #pragma unroll
            for (int j = 5; j < 10; ++j) {
                ev[j] = *reinterpret_cast<const float4*>(Erow + 4 * j);
                bv[j] = *reinterpret_cast<const float4*>(B2 + d0 + 4 * j);
            }
        } else {
            #pragma unroll
            for (int j = 5; j < 10; ++j) {
                ev[j] = make_float4(0.f, 0.f, 0.f, 0.f);
                bv[j] = make_float4(0.f, 0.f, 0.f, 0.f);
            }
        }
        #pragma unroll
        for (int j = 0; j < 10; ++j) {
            e[j].x = ev[j].x * bv[j].x * cmask;
            e[j].y = ev[j].y * bv[j].y * cmask;
            e[j].z = ev[j].z * bv[j].z * cmask;
            e[j].w = ev[j].w * bv[j].w * cmask;
        }
    }

    // ---- score loop over valid prefix: clean bounds, batched loads ----
    const float* Tn = T + (size_t)n * WIN * D;
    #pragma unroll 2
    for (int w = 0; w < L; ++w) {
        const float* Trow = Tn + (size_t)w * D + d0;
        float4 tt[10];
        #pragma unroll
        for (int j = 0; j < 5; ++j)
            tt[j] = *reinterpret_cast<const float4*>(Trow + 4 * j);
        if (full) {
            #pragma unroll
            for (int j = 5; j < 10; ++j)
                tt[j] = *reinterpret_cast<const float4*>(Trow + 4 * j);
        }
        float a0 = 0.f, a1 = 0.f;
        #pragma unroll
        for (int j = 0; j < 5; ++j) {
            float v = e[j].x * tt[j].x + e[j].y * tt[j].y
                    + e[j].z * tt[j].z + e[j].w * tt[j].w;
            if (j & 1) a1 += v; else a0 += v;
        }
        if (full) {
            #pragma unroll
            for (int j = 5; j < 10; ++j) {
                float v = e[j].x * tt[j].x + e[j].y * tt[j].y
                        + e[j].z * tt[j].z + e[j].w * tt[j].w;
                if (j & 1) a1 += v; else a0 += v;
            }
        }
        float acc = a0 + a1;
        acc += __shfl_xor(acc, 32);
        if (lane < 32) part[wv][cg][w] = acc;
    }
    __syncthreads();

    // ---- token score = max over candidates (valid prefix only) ----
    if (tid < WIN) {
        float m = NEGV;
        if (tid < L) {
            m = -__builtin_inff();
            for (int c = 0; c < NC; ++c) {
                float s = part[0][c][tid] + part[1][c][tid]
                        + part[2][c][tid] + part[3][c][tid];
                m = fmaxf(m, s);
            }
        }
        ts[tid] = m;
    }
    __syncthreads();

    // ---- top-25 (wave 0, lower-index tie-break) + double-normalized softmax ----
    if (tid < 64) {
        float va = ts[tid];
        float vb = (tid + 64 < WIN) ? ts[tid + 64] : -__builtin_inff();
        float mx = 0.f;
        for (int t = 0; t < TOPK; ++t) {
            float v0; int i0;
            if (vb > va) { v0 = vb; i0 = tid + 64; } else { v0 = va; i0 = tid; }
            #pragma unroll
            for (int s = 32; s >= 1; s >>= 1) {
                float ov = __shfl_xor(v0, s);
                int   oi = __shfl_xor(i0, s);
                if (ov > v0 || (ov == v0 && oi < i0)) { v0 = ov; i0 = oi; }
            }
            if (t == 0) mx = v0;
            if (tid == 0) { bscore[t] = v0; bidx[t] = i0; }
            if (i0 == tid) va = -__builtin_inff();
            else if (i0 == tid + 64) vb = -__builtin_inff();
        }
        float sc = (tid < TOPK) ? bscore[tid] : 0.f;
        float p  = (tid < TOPK) ? expf(sc - mx) : 0.f;
        float s1 = p;
        #pragma unroll
        for (int s = 32; s >= 1; s >>= 1) s1 += __shfl_xor(s1, s);
        p = p / s1;
        float s2 = p;   // reference renormalizes a second time
        #pragma unroll
        for (int s = 32; s >= 1; s >>= 1) s2 += __shfl_xor(s2, s);
        p = p / s2;
        if (tid < TOPK) bprob[tid] = p;
    }
    __syncthreads();

    // ---- fcs: probability-weighted sum of best tokens ----
    float4 fc[10];
    #pragma unroll
    for (int j = 0; j < 10; ++j) fc[j] = make_float4(0.f, 0.f, 0.f, 0.f);
    for (int t = 0; t < TOPK; ++t) {
        const float p = bprob[t];
        const float* Trow = Tn + (size_t)bidx[t] * D + d0;
        float4 tt[10];
        #pragma unroll
        for (int j = 0; j < 5; ++j)
            tt[j] = *reinterpret_cast<const float4*>(Trow + 4 * j);
        if (full) {
            #pragma unroll
            for (int j = 5; j < 10; ++j)
                tt[j] = *reinterpret_cast<const float4*>(Trow + 4 * j);
        }
        #pragma unroll
        for (int j = 0; j < 5; ++j) {
            fc[j].x += p * tt[j].x; fc[j].y += p * tt[j].y;
            fc[j].z += p * tt[j].z; fc[j].w += p * tt[j].w;
        }
        if (full) {
            #pragma unroll
            for (int j = 5; j < 10; ++j) {
                fc[j].x += p * tt[j].x; fc[j].y += p * tt[j].y;
                fc[j].z += p * tt[j].z; fc[j].w += p * tt[j].w;
            }
        }
    }

    // ---- vals[c] = sum_d E_raw[c,d] * B1[d] * fcs[d] ----
    float acc2 = 0.f;
    {
        const float* Erow = E + ((size_t)n * NC + (cok ? cg : 0)) * D + d0;
        float4 ev[10], bv[10];
        #pragma unroll
        for (int j = 0; j < 5; ++j) {
            ev[j] = *reinterpret_cast<const float4*>(Erow + 4 * j);
            bv[j] = *reinterpret_cast<const float4*>(B1 + d0 + 4 * j);
        }
        if (full) {
            #pragma unroll
            for (int j = 5; j < 10; ++j) {
                ev[j] = *reinterpret_cast<const float4*>(Erow + 4 * j);
                bv[j] = *reinterpret_cast<const float4*>(B1 + d0 + 4 * j);
            }
        } else {
            #pragma unroll
            for (int j = 5; j < 10; ++j) {
                ev[j] = make_float4(0.f, 0.f, 0.f, 0.f);
                bv[j] = make_float4(0.f, 0.f, 0.f, 0.f);
            }
        }
        #pragma unroll
        for (int j = 0; j < 10; ++j) {
            acc2 += ev[j].x * bv[j].x * fc[j].x + ev[j].y * bv[j].y * fc[j].y
                  + ev[j].z * bv[j].z * fc[j].z + ev[j].w * bv[j].w * fc[j].w;
        }
    }
    acc2 *= cmask;
    acc2 += __shfl_xor(acc2, 32);
    if (lane < 32) vred[wv][cg] = acc2;
    __syncthreads();
    if (tid < NC) {
        out[(size_t)n * NC + tid] =
            vred[0][tid] + vred[1][tid] + vred[2][tid] + vred[3][tid];
    }
}

extern "C" void kernel_launch(void* const* d_in, const int* in_sizes, int n_in,
                              void* d_out, int out_size, void* d_ws, size_t ws_size,
                              hipStream_t stream)
{
    const float* E  = (const float*)d_in[0];
    const float* T  = (const float*)d_in[1];
    const void*  M  = d_in[2];
    const float* B1 = (const float*)d_in[3];
    const float* B2 = (const float*)d_in[4];
    float* out = (float*)d_out;
    const int n = in_sizes[0] / (NC * D);   // number of mentions
    fused_mention_kernel<<<n, 256, 0, stream>>>(E, T, M, B1, B2, out);
}

// Round 3
// 629.472 us; speedup vs baseline: 2.5700x; 1.6859x over previous
//
#include <hip/hip_runtime.h>
#include <math.h>

#define NC    30
#define D     300
#define WIN   100
#define TOPK  25
#define NEGV  -1e10f
#define TTOK  8              // tokens per staged LDS tile

#if defined(__has_builtin)
#if __has_builtin(__builtin_amdgcn_global_load_lds)
#define HAVE_DMA 1
#endif
#endif

__global__ __launch_bounds__(256, 4)
void fused_mention_kernel(const float* __restrict__ E,
                          const float* __restrict__ T,
                          const void*  __restrict__ maskp,
                          const float* __restrict__ B1,
                          const float* __restrict__ B2,
                          float* __restrict__ out)
{
    const int n    = blockIdx.x;
    const int tid  = threadIdx.x;
    const int dg   = tid >> 5;        // 0..7  d-slice group
    const int cg   = tid & 31;        // 0..31 candidate (30 real + 2 pad)
    const int wv   = tid >> 6;        // wave id 0..3
    const int lane = tid & 63;
    const int d0   = dg * 40;         // groups 0..6: 40 floats; group 7: 20
    const bool cok  = (cg < NC);
    const bool full = (dg < 7);
    const float cmask = cok ? 1.f : 0.f;

    __shared__ float Ttile[2][TTOK * D];        // 19.2 KB double-buffered T tile
    __shared__ float part[4][32][TTOK + 1];     // 4.6 KB, stride 9 -> conflict-free
    __shared__ float ts[WIN];
    __shared__ float bscore[TOPK];
    __shared__ int   bidx[TOPK];
    __shared__ float bprob[TOPK];
    __shared__ float vred[4][32];
    __shared__ int   mmode;
    __shared__ int   lcnt[2];

    // ---- mask dtype detect + ts init ----
    if (tid == 0) mmode = 0;
    if (tid < WIN) ts[tid] = NEGV;
    __syncthreads();
    {
        const unsigned char* mb = (const unsigned char*)maskp;
        int found = 0;
        for (int i = tid; i < 4096; i += 256)
            if ((i & 3) && mb[i]) found = 1;
        if (found) mmode = 1;
    }
    __syncthreads();

    // ---- valid-prefix length L via 2-wave ballot ----
    if (tid < 128) {
        int v = 0;
        if (tid < WIN) {
            if (mmode) v = ((const unsigned char*)maskp)[(size_t)n * WIN + tid] != 0;
            else       v = ((const int*)maskp)[(size_t)n * WIN + tid] != 0;
        }
        unsigned long long b = __ballot(v);
        if (lane == 0) lcnt[wv] = __popcll(b);
    }

    const float* Tn = T + (size_t)n * WIN * D;

    // ---- stage tile 0 (DMA, overlaps E load below) ----
#ifdef HAVE_DMA
    {
        const int nf4 = TTOK * (D / 4);   // tile 0 always full (WIN >= 8)
        const float* g = Tn;
        float* dst = &Ttile[0][0];
        for (int i = tid; i < nf4; i += 256) {
            __builtin_amdgcn_global_load_lds(
                (const __attribute__((address_space(1))) void*)(g + 4 * i),
                (__attribute__((address_space(3))) void*)(dst + 4 * i),
                16, 0, 0);
        }
    }
#else
    {
        const int nf4 = TTOK * (D / 4);
        const float* g = Tn;
        for (int i = tid; i < nf4; i += 256)
            *reinterpret_cast<float4*>(&Ttile[0][4 * i]) =
                *reinterpret_cast<const float4*>(g + 4 * i);
    }
#endif

    // ---- E slice -> registers, fold B_diag2 ----
    float4 e[10];
    {
        const float* Erow = E + ((size_t)n * NC + (cok ? cg : 0)) * D + d0;
        float4 ev[10], bv[10];
        #pragma unroll
        for (int j = 0; j < 5; ++j) {
            ev[j] = *reinterpret_cast<const float4*>(Erow + 4 * j);
            bv[j] = *reinterpret_cast<const float4*>(B2 + d0 + 4 * j);
        }
        if (full) {
            #pragma unroll
            for (int j = 5; j < 10; ++j) {
                ev[j] = *reinterpret_cast<const float4*>(Erow + 4 * j);
                bv[j] = *reinterpret_cast<const float4*>(B2 + d0 + 4 * j);
            }
        } else {
            #pragma unroll
            for (int j = 5; j < 10; ++j) {
                ev[j] = make_float4(0.f, 0.f, 0.f, 0.f);
                bv[j] = make_float4(0.f, 0.f, 0.f, 0.f);
            }
        }
        #pragma unroll
        for (int j = 0; j < 10; ++j) {
            e[j].x = ev[j].x * bv[j].x * cmask;
            e[j].y = ev[j].y * bv[j].y * cmask;
            e[j].z = ev[j].z * bv[j].z * cmask;
            e[j].w = ev[j].w * bv[j].w * cmask;
        }
    }

    __syncthreads();                       // lcnt ready + tile 0 DMA drained
    const int L = lcnt[0] + lcnt[1];
    const int ntiles = (L + TTOK - 1) / TTOK;

    // ---- main tiled score loop (double-buffered DMA) ----
    int cur = 0;
    for (int t = 0; t < ntiles; ++t) {
        const int t0 = t * TTOK;
        // issue next tile's DMA into the other buffer
        if (t + 1 < ntiles) {
            const int t1 = t0 + TTOK;
            const int rows = min(TTOK, WIN - t1);   // stay in-bounds of T
            const int nf4 = rows * (D / 4);
            const float* g = Tn + (size_t)t1 * D;
            float* dst = &Ttile[cur ^ 1][0];
#ifdef HAVE_DMA
            for (int i = tid; i < nf4; i += 256) {
                __builtin_amdgcn_global_load_lds(
                    (const __attribute__((address_space(1))) void*)(g + 4 * i),
                    (__attribute__((address_space(3))) void*)(dst + 4 * i),
                    16, 0, 0);
            }
#else
            for (int i = tid; i < nf4; i += 256)
                *reinterpret_cast<float4*>(dst + 4 * i) =
                    *reinterpret_cast<const float4*>(g + 4 * i);
#endif
        }
        // score this tile from LDS
        const int wcnt = min(TTOK, L - t0);
        const float* Tl = &Ttile[cur][0];
        for (int w8 = 0; w8 < wcnt; ++w8) {
            const float* Trow = Tl + w8 * D + d0;
            float4 tt[10];
            #pragma unroll
            for (int j = 0; j < 5; ++j)
                tt[j] = *reinterpret_cast<const float4*>(Trow + 4 * j);
            if (full) {
                #pragma unroll
                for (int j = 5; j < 10; ++j)
                    tt[j] = *reinterpret_cast<const float4*>(Trow + 4 * j);
            }
            float a0 = 0.f, a1 = 0.f;
            #pragma unroll
            for (int j = 0; j < 5; ++j) {
                float v = e[j].x * tt[j].x + e[j].y * tt[j].y
                        + e[j].z * tt[j].z + e[j].w * tt[j].w;
                if (j & 1) a1 += v; else a0 += v;
            }
            if (full) {
                #pragma unroll
                for (int j = 5; j < 10; ++j) {
                    float v = e[j].x * tt[j].x + e[j].y * tt[j].y
                            + e[j].z * tt[j].z + e[j].w * tt[j].w;
                    if (j & 1) a1 += v; else a0 += v;
                }
            }
            float acc = a0 + a1;
            acc += __shfl_xor(acc, 32);
            if (lane < 32) part[wv][cg][w8] = acc;
        }
        __syncthreads();                   // part visible (also drains DMA)
        // per-tile token max over candidates
        {
            const int w8 = tid >> 5;
            const int c  = tid & 31;
            if (w8 < wcnt) {
                float s = ((part[0][c][w8] + part[1][c][w8])
                          + part[2][c][w8]) + part[3][c][w8];
                if (c >= NC) s = -__builtin_inff();
                #pragma unroll
                for (int m = 16; m >= 1; m >>= 1)
                    s = fmaxf(s, __shfl_xor(s, m));
                if (c == 0) ts[t0 + w8] = s;
            }
        }
        __syncthreads();                   // part reusable next tile
        cur ^= 1;
    }

    // ---- top-25 (wave 0, lower-index tie-break) + double-normalized softmax ----
    if (tid < 64) {
        float va = ts[tid];
        float vb = (tid + 64 < WIN) ? ts[tid + 64] : -__builtin_inff();
        float mx = 0.f;
        for (int t = 0; t < TOPK; ++t) {
            float v0; int i0;
            if (vb > va) { v0 = vb; i0 = tid + 64; } else { v0 = va; i0 = tid; }
            #pragma unroll
            for (int s = 32; s >= 1; s >>= 1) {
                float ov = __shfl_xor(v0, s);
                int   oi = __shfl_xor(i0, s);
                if (ov > v0 || (ov == v0 && oi < i0)) { v0 = ov; i0 = oi; }
            }
            if (t == 0) mx = v0;
            if (tid == 0) { bscore[t] = v0; bidx[t] = i0; }
            if (i0 == tid) va = -__builtin_inff();
            else if (i0 == tid + 64) vb = -__builtin_inff();
        }
        float sc = (tid < TOPK) ? bscore[tid] : 0.f;
        float p  = (tid < TOPK) ? expf(sc - mx) : 0.f;
        float s1 = p;
        #pragma unroll
        for (int s = 32; s >= 1; s >>= 1) s1 += __shfl_xor(s1, s);
        p = p / s1;
        float s2 = p;   // reference renormalizes a second time
        #pragma unroll
        for (int s = 32; s >= 1; s >>= 1) s2 += __shfl_xor(s2, s);
        p = p / s2;
        if (tid < TOPK) bprob[tid] = p;
    }
    __syncthreads();

    // ---- fcs: probability-weighted sum of best tokens (rows are L2/L3 hot) ----
    float4 fc[10];
    #pragma unroll
    for (int j = 0; j < 10; ++j) fc[j] = make_float4(0.f, 0.f, 0.f, 0.f);
    for (int t = 0; t < TOPK; ++t) {
        const float p = bprob[t];
        const float* Trow = Tn + (size_t)bidx[t] * D + d0;
        float4 tt[10];
        #pragma unroll
        for (int j = 0; j < 5; ++j)
            tt[j] = *reinterpret_cast<const float4*>(Trow + 4 * j);
        if (full) {
            #pragma unroll
            for (int j = 5; j < 10; ++j)
                tt[j] = *reinterpret_cast<const float4*>(Trow + 4 * j);
        }
        #pragma unroll
        for (int j = 0; j < 5; ++j) {
            fc[j].x += p * tt[j].x; fc[j].y += p * tt[j].y;
            fc[j].z += p * tt[j].z; fc[j].w += p * tt[j].w;
        }
        if (full) {
            #pragma unroll
            for (int j = 5; j < 10; ++j) {
                fc[j].x += p * tt[j].x; fc[j].y += p * tt[j].y;
                fc[j].z += p * tt[j].z; fc[j].w += p * tt[j].w;
            }
        }
    }

    // ---- vals[c] = sum_d E_raw[c,d] * B1[d] * fcs[d] (E re-read, L3-hot) ----
    float acc2 = 0.f;
    {
        const float* Erow = E + ((size_t)n * NC + (cok ? cg : 0)) * D + d0;
        float4 ev[10], bv[10];
        #pragma unroll
        for (int j = 0; j < 5; ++j) {
            ev[j] = *reinterpret_cast<const float4*>(Erow + 4 * j);
            bv[j] = *reinterpret_cast<const float4*>(B1 + d0 + 4 * j);
        }
        if (full) {
            #pragma unroll
            for (int j = 5; j < 10; ++j) {
                ev[j] = *reinterpret_cast<const float4*>(Erow + 4 * j);
                bv[j] = *reinterpret_cast<const float4*>(B1 + d0 + 4 * j);
            }
        } else {
            #pragma unroll
            for (int j = 5; j < 10; ++j) {
                ev[j] = make_float4(0.f, 0.f, 0.f, 0.f);
                bv[j] = make_float4(0.f, 0.f, 0.f, 0.f);
            }
        }
        #pragma unroll
        for (int j = 0; j < 10; ++j) {
            acc2 += ev[j].x * bv[j].x * fc[j].x + ev[j].y * bv[j].y * fc[j].y
                  + ev[j].z * bv[j].z * fc[j].z + ev[j].w * bv[j].w * fc[j].w;
        }
    }
    acc2 *= cmask;
    acc2 += __shfl_xor(acc2, 32);
    if (lane < 32) vred[wv][cg] = acc2;
    __syncthreads();
    if (tid < NC) {
        out[(size_t)n * NC + tid] =
            vred[0][tid] + vred[1][tid] + vred[2][tid] + vred[3][tid];
    }
}

extern "C" void kernel_launch(void* const* d_in, const int* in_sizes, int n_in,
                              void* d_out, int out_size, void* d_ws, size_t ws_size,
                              hipStream_t stream)
{
    const float* E  = (const float*)d_in[0];
    const float* T  = (const float*)d_in[1];
    const void*  M  = d_in[2];
    const float* B1 = (const float*)d_in[3];
    const float* B2 = (const float*)d_in[4];
    float* out = (float*)d_out;
    const int n = in_sizes[0] / (NC * D);   // number of mentions
    fused_mention_kernel<<<n, 256, 0, stream>>>(E, T, M, B1, B2, out);
}